// Round 12
// baseline (329.760 us; speedup 1.0000x reference)
//
#include <hip/hip_runtime.h>
#include <hip/hip_bf16.h>
#include <math.h>

#define N_NODES 50000
#define NE      800000
#define ETOT    (NE + N_NODES)   // edges + self loops = 850000
#define F       128              // F_in == H*C
#define NHEAD   4
#define NEG     0.2f

#define SCAN_B 256
#define NBLK   ((N_NODES + SCAN_B - 1) / SCAN_B)   // 196

typedef __attribute__((ext_vector_type(4))) float f32x4;
typedef _Float16 f16x8 __attribute__((ext_vector_type(8)));

// async global->LDS, 16B per lane; LDS dest = wave-uniform base + lane*16
__device__ __forceinline__ void gld16(const void* g, void* l) {
    __builtin_amdgcn_global_load_lds(
        (const __attribute__((address_space(1))) unsigned int*)g,
        (__attribute__((address_space(3))) unsigned int*)l, 16, 0, 0);
}

// ---------------- CSR build (atomic-free fill via rank trick) ----------------

__global__ void k_deg(const int* __restrict__ ei, int* __restrict__ deg,
                      int* __restrict__ rank) {
    int i = blockIdx.x * blockDim.x + threadIdx.x;
    if (i < ETOT) {
        int d = (i < NE) ? ei[NE + i] : (i - NE);
        rank[i] = atomicAdd(&deg[d], 1);
    }
}

__global__ void k_scan1(const int* __restrict__ deg, int* __restrict__ bsum) {
    __shared__ int sm[SCAN_B];
    int i = blockIdx.x * SCAN_B + threadIdx.x;
    sm[threadIdx.x] = (i < N_NODES) ? deg[i] : 0;
    __syncthreads();
    for (int s = SCAN_B / 2; s > 0; s >>= 1) {
        if (threadIdx.x < s) sm[threadIdx.x] += sm[threadIdx.x + s];
        __syncthreads();
    }
    if (threadIdx.x == 0) bsum[blockIdx.x] = sm[0];
}

__global__ void k_scan2(int* __restrict__ bsum) {
    __shared__ int sm[SCAN_B];
    int t = threadIdx.x;
    int v = (t < NBLK) ? bsum[t] : 0;
    sm[t] = v; __syncthreads();
    for (int s = 1; s < SCAN_B; s <<= 1) {
        int a = (t >= s) ? sm[t - s] : 0;
        __syncthreads();
        sm[t] += a;
        __syncthreads();
    }
    if (t < NBLK) bsum[t] = sm[t] - v;  // exclusive
}

__global__ void k_scan3(const int* __restrict__ deg, const int* __restrict__ bsum,
                        int* __restrict__ rowptr) {
    __shared__ int sm[SCAN_B];
    int t = threadIdx.x;
    int i = blockIdx.x * SCAN_B + t;
    int v = (i < N_NODES) ? deg[i] : 0;
    sm[t] = v; __syncthreads();
    for (int s = 1; s < SCAN_B; s <<= 1) {
        int a = (t >= s) ? sm[t - s] : 0;
        __syncthreads();
        sm[t] += a;
        __syncthreads();
    }
    int excl = sm[t] - v + bsum[blockIdx.x];
    if (i < N_NODES) rowptr[i] = excl;
    if (i == N_NODES - 1) rowptr[N_NODES] = excl + v;
}

__global__ void k_fill(const int* __restrict__ ei, const int* __restrict__ rowptr,
                       const int* __restrict__ rank, int* __restrict__ col) {
    int i = blockIdx.x * blockDim.x + threadIdx.x;
    if (i < ETOT) {
        int s, d;
        if (i < NE) { s = ei[i]; d = ei[NE + i]; }
        else        { s = i - NE; d = s; }
        col[rowptr[d] + rank[i]] = s;
    }
}

// ---------------- weight pre-split: Ws (fp32) -> f16 hi + lo ----------------
// Dropped cross term in the GEMM is XlWl ~ 2^-22 relative — tighter than the
// old in-kernel bf16 split (2^-16). Enables pure-DMA W staging below.

__global__ void k_prep(const float* __restrict__ Ws, _Float16* __restrict__ Wh,
                       _Float16* __restrict__ Wl) {
    int i = blockIdx.x * blockDim.x + threadIdx.x;   // < 3*128*128
    float w = Ws[i];
    _Float16 h = (_Float16)w;
    Wh[i] = h;
    Wl[i] = (_Float16)(w - (float)h);
}

// ---------------- GEMM common shape ----------------
// 64 nodes/block, 4 waves; wave w owns rows w*16..w*16+15, all 128 outputs
// (8 n-tiles of 16). LDS layout is lane-natural: unit(row,quad) = row*4+quad,
// 16B/unit — global_load_lds writes it directly (base + lane*16), and b128
// fragment reads spread evenly over all 32 banks (8-way = the 1024B/wave
// minimum). Double-buffered; ONE barrier per k-tile (the __syncthreads vmcnt
// drain doubles as the DMA completion wait). Plain launch_bounds (round-3:
// 2nd arg forces spills).

#define GM 64

__device__ __forceinline__ void gemm_epilogue(
        f32x4* acc, const float* a_s, const float* a_d,
        _Float16* hout, float* asrc, float* adst,
        int bm, int wv, int fm, int fq) {
    float as_v[8], ad_v[8];
#pragma unroll
    for (int nt = 0; nt < 8; nt++) {
        as_v[nt] = a_s[nt * 16 + fm];
        ad_v[nt] = a_d[nt * 16 + fm];
    }
#pragma unroll
    for (int r = 0; r < 4; r++) {
        int n = bm + wv * 16 + fq * 4 + r;
        bool ok = (n < N_NODES);
        if (ok) {
#pragma unroll
            for (int nt = 0; nt < 8; nt++)
                hout[(size_t)n * F + nt * 16 + fm] = (_Float16)acc[nt][r];
        }
        float ps[4], pd[4];
#pragma unroll
        for (int hh = 0; hh < 4; hh++) {
            ps[hh] = acc[2 * hh][r] * as_v[2 * hh] + acc[2 * hh + 1][r] * as_v[2 * hh + 1];
            pd[hh] = acc[2 * hh][r] * ad_v[2 * hh] + acc[2 * hh + 1][r] * ad_v[2 * hh + 1];
        }
#pragma unroll
        for (int s = 1; s < 16; s <<= 1) {
#pragma unroll
            for (int hh = 0; hh < 4; hh++) {
                ps[hh] += __shfl_xor(ps[hh], s);
                pd[hh] += __shfl_xor(pd[hh], s);
            }
        }
        if (ok && fm == 0) {
            *(float4*)&asrc[n * 4] = make_float4(ps[0], ps[1], ps[2], ps[3]);
            *(float4*)&adst[n * 4] = make_float4(pd[0], pd[1], pd[2], pd[3]);
        }
    }
}

// ---------------- layer-1 GEMM: fp32 X (in-reg f16 split), W via DMA ----------

__global__ __launch_bounds__(256) void k_gemm32(const float* __restrict__ X,
                                                const _Float16* __restrict__ Wh,
                                                const _Float16* __restrict__ Wl,
                                                const float* __restrict__ a_s,
                                                const float* __restrict__ a_d,
                                                _Float16* __restrict__ hout,
                                                float* __restrict__ asrc,
                                                float* __restrict__ adst) {
    __shared__ _Float16 Ah[2][64 * 32], Al[2][64 * 32];     // 4KB each buf
    __shared__ _Float16 Bh[2][128 * 32], Bl[2][128 * 32];   // 8KB each buf
    int tid = threadIdx.x;
    int lane = tid & 63, wv = tid >> 6;
    int bm = blockIdx.x * GM;

    int sr = lane >> 2, sq = lane & 3;            // staged row-in-16, quad
    int arow = bm + wv * 16 + sr;
    bool xok = (arow < N_NODES);
    const float*    xg  = X  + (size_t)arow * F + sq * 8;
    const _Float16* bh0 = Wh + (size_t)(wv * 16 + sr) * F + sq * 8;
    const _Float16* bh1 = Wh + (size_t)(64 + wv * 16 + sr) * F + sq * 8;
    const _Float16* bl0 = Wl + (size_t)(wv * 16 + sr) * F + sq * 8;
    const _Float16* bl1 = Wl + (size_t)(64 + wv * 16 + sr) * F + sq * 8;

    int fm = lane & 15, fq = lane >> 4;
    int aoff = ((wv * 16 + fm) * 4 + fq) * 8;     // halfs

    f32x4 acc[8];
#pragma unroll
    for (int nt = 0; nt < 8; nt++) acc[nt] = (f32x4){0.f, 0.f, 0.f, 0.f};

    float4 xp0, xp1;
    float4 z4 = make_float4(0.f, 0.f, 0.f, 0.f);
    auto xload = [&](int k0) {
        xp0 = xok ? *(const float4*)(xg + k0)     : z4;
        xp1 = xok ? *(const float4*)(xg + k0 + 4) : z4;
    };
    auto xstore = [&](int buf) {                  // split fp32 -> f16 hi/lo
        float f[8] = {xp0.x, xp0.y, xp0.z, xp0.w, xp1.x, xp1.y, xp1.z, xp1.w};
        f16x8 h, l;
#pragma unroll
        for (int j = 0; j < 8; j++) {
            _Float16 hh = (_Float16)f[j];
            h[j] = hh;
            l[j] = (_Float16)(f[j] - (float)hh);
        }
        *(f16x8*)&Ah[buf][(size_t)(wv * 16 + sr) * 32 + sq * 8] = h;
        *(f16x8*)&Al[buf][(size_t)(wv * 16 + sr) * 32 + sq * 8] = l;
    };
    auto wstage = [&](int k0, int buf) {          // 4 DMA issues per wave
        gld16(bh0 + k0, &Bh[buf][wv * 512]);
        gld16(bh1 + k0, &Bh[buf][2048 + wv * 512]);
        gld16(bl0 + k0, &Bl[buf][wv * 512]);
        gld16(bl1 + k0, &Bl[buf][2048 + wv * 512]);
    };

    xload(0); wstage(0, 0); xstore(0);
    __syncthreads();

#pragma unroll
    for (int t = 0; t < 4; t++) {
        int buf = t & 1;
        if (t < 3) { xload((t + 1) * 32); wstage((t + 1) * 32, buf ^ 1); }
        f16x8 ah = *(f16x8*)&Ah[buf][aoff];
        f16x8 al = *(f16x8*)&Al[buf][aoff];
#pragma unroll
        for (int nt = 0; nt < 8; nt++) {
            int bo = ((nt * 16 + fm) * 4 + fq) * 8;
            f16x8 bh = *(f16x8*)&Bh[buf][bo];
            f16x8 bl = *(f16x8*)&Bl[buf][bo];
            acc[nt] = __builtin_amdgcn_mfma_f32_16x16x32_f16(ah, bh, acc[nt], 0, 0, 0);
            acc[nt] = __builtin_amdgcn_mfma_f32_16x16x32_f16(ah, bl, acc[nt], 0, 0, 0);
            acc[nt] = __builtin_amdgcn_mfma_f32_16x16x32_f16(al, bh, acc[nt], 0, 0, 0);
        }
        if (t < 3) xstore(buf ^ 1);
        __syncthreads();   // drains DMA (vmcnt) + orders LDS for next tile
    }

    gemm_epilogue(acc, a_s, a_d, hout, asrc, adst, bm, wv, fm, fq);
}

// ---------------- layer-2/3 GEMM: fp16 X — ALL staging via global_load_lds ----

__global__ __launch_bounds__(256) void k_gemm16(const _Float16* __restrict__ X,
                                                const _Float16* __restrict__ Wh,
                                                const _Float16* __restrict__ Wl,
                                                const float* __restrict__ a_s,
                                                const float* __restrict__ a_d,
                                                _Float16* __restrict__ hout,
                                                float* __restrict__ asrc,
                                                float* __restrict__ adst) {
    __shared__ _Float16 Ab[2][64 * 32];                     // 4KB each buf
    __shared__ _Float16 Bh[2][128 * 32], Bl[2][128 * 32];   // 8KB each buf
    int tid = threadIdx.x;
    int lane = tid & 63, wv = tid >> 6;
    int bm = blockIdx.x * GM;

    int sr = lane >> 2, sq = lane & 3;
    int arow = bm + wv * 16 + sr;   // OOB rows read d_ws slack (results discarded)
    const _Float16* ag  = X  + (size_t)arow * F + sq * 8;
    const _Float16* bh0 = Wh + (size_t)(wv * 16 + sr) * F + sq * 8;
    const _Float16* bh1 = Wh + (size_t)(64 + wv * 16 + sr) * F + sq * 8;
    const _Float16* bl0 = Wl + (size_t)(wv * 16 + sr) * F + sq * 8;
    const _Float16* bl1 = Wl + (size_t)(64 + wv * 16 + sr) * F + sq * 8;

    int fm = lane & 15, fq = lane >> 4;
    int aoff = ((wv * 16 + fm) * 4 + fq) * 8;

    f32x4 acc[8];
#pragma unroll
    for (int nt = 0; nt < 8; nt++) acc[nt] = (f32x4){0.f, 0.f, 0.f, 0.f};

    auto stage = [&](int k0, int buf) {           // 5 DMA issues per wave
        gld16(ag  + k0, &Ab[buf][wv * 512]);
        gld16(bh0 + k0, &Bh[buf][wv * 512]);
        gld16(bh1 + k0, &Bh[buf][2048 + wv * 512]);
        gld16(bl0 + k0, &Bl[buf][wv * 512]);
        gld16(bl1 + k0, &Bl[buf][2048 + wv * 512]);
    };

    stage(0, 0);
    __syncthreads();

#pragma unroll
    for (int t = 0; t < 4; t++) {
        int buf = t & 1;
        if (t < 3) stage((t + 1) * 32, buf ^ 1);
        f16x8 ah = *(f16x8*)&Ab[buf][aoff];
#pragma unroll
        for (int nt = 0; nt < 8; nt++) {
            int bo = ((nt * 16 + fm) * 4 + fq) * 8;
            f16x8 bh = *(f16x8*)&Bh[buf][bo];
            f16x8 bl = *(f16x8*)&Bl[buf][bo];
            acc[nt] = __builtin_amdgcn_mfma_f32_16x16x32_f16(ah, bh, acc[nt], 0, 0, 0);
            acc[nt] = __builtin_amdgcn_mfma_f32_16x16x32_f16(ah, bl, acc[nt], 0, 0, 0);
        }
        __syncthreads();   // drains DMA (vmcnt) + protects buffer reuse
    }

    gemm_epilogue(acc, a_s, a_d, hout, asrc, adst, bm, wv, fm, fq);
}

// ---------------- fused softmax + aggregate v4 (no-max softmax) ----------------

#define EPAD 68

__global__ __launch_bounds__(256) void k_aggr(const _Float16* __restrict__ h,
                                              const float* __restrict__ asrc,
                                              const float* __restrict__ adst,
                                              const int* __restrict__ rowptr,
                                              const int* __restrict__ col,
                                              const float* __restrict__ bias,
                                              _Float16* __restrict__ xout) {
    __shared__ int   scol[4][64];
    __shared__ float swT[4][4 * EPAD];
    int wave = threadIdx.x >> 6;
    int lane = threadIdx.x & 63;
    int n = blockIdx.x * 4 + wave;
    if (n >= N_NODES) return;
    int wl = lane & 15;        // channel-octet: channels wl*8 .. wl*8+7
    int he = lane >> 4;        // gather: edge sub-index; reduce: head id
    int hc = wl >> 2;          // head of this lane's channels
    int beg = rowptr[n], end = rowptr[n + 1];
    float4 ad4 = *(const float4*)&adst[n * 4];

    float s_run = 0.f;
    float acc[8];
#pragma unroll
    for (int j = 0; j < 8; j++) acc[j] = 0.f;

    for (int base = beg; base < end; base += 64) {
        int cnt = end - base; if (cnt > 64) cnt = 64;
        int sidx = 0;
        float4 w4 = make_float4(0.f, 0.f, 0.f, 0.f);
        if (lane < cnt) {
            sidx = col[base + lane];
            float4 av = *(const float4*)&asrc[sidx * 4];
            float ex = av.x + ad4.x, ey = av.y + ad4.y,
                  ez = av.z + ad4.z, ew = av.w + ad4.w;
            ex = (ex > 0.f) ? ex : NEG * ex;
            ey = (ey > 0.f) ? ey : NEG * ey;
            ez = (ez > 0.f) ? ez : NEG * ez;
            ew = (ew > 0.f) ? ew : NEG * ew;
            w4.x = __expf(ex); w4.y = __expf(ey);
            w4.z = __expf(ez); w4.w = __expf(ew);
        }
        scol[wave][lane] = sidx;
        swT[wave][0 * EPAD + lane] = w4.x;
        swT[wave][1 * EPAD + lane] = w4.y;
        swT[wave][2 * EPAD + lane] = w4.z;
        swT[wave][3 * EPAD + lane] = w4.w;
        __builtin_amdgcn_sched_barrier(0);   // pin LDS write->read order
        float4 wv4 = *(float4*)&swT[wave][he * EPAD + wl * 4];
        float S = (wv4.x + wv4.y) + (wv4.z + wv4.w);
#pragma unroll
        for (int s = 1; s < 16; s <<= 1) S += __shfl_xor(S, s);
        s_run += S;
        __builtin_amdgcn_sched_barrier(0);
#pragma unroll 2
        for (int p = 0; p < cnt; p += 4) {
            int ep = p + he;
            int s = scol[wave][ep];
            float wgt = swT[wave][hc * EPAD + ep];
            f16x8 hv = *(const f16x8*)&h[(size_t)s * F + wl * 8];
#pragma unroll
            for (int j = 0; j < 8; j++)
                acc[j] = fmaf(wgt, (float)hv[j], acc[j]);
        }
        __builtin_amdgcn_sched_barrier(0);   // gather reads before next chunk
    }

#pragma unroll
    for (int j = 0; j < 8; j++) {
        acc[j] += __shfl_xor(acc[j], 16);
        acc[j] += __shfl_xor(acc[j], 32);
    }
    float sv = __shfl(s_run, hc * 16);
    float inv = 1.f / (sv + 1e-16f);
    float4 b0 = *(const float4*)&bias[wl * 8];
    float4 b1 = *(const float4*)&bias[wl * 8 + 4];
    float bb[8] = {b0.x, b0.y, b0.z, b0.w, b1.x, b1.y, b1.z, b1.w};
    if (he == 0) {
        f16x8 st;
#pragma unroll
        for (int j = 0; j < 8; j++)
            st[j] = (_Float16)fmaxf(fmaf(acc[j], inv, bb[j]), 0.f);
        *(f16x8*)&xout[(size_t)n * F + wl * 8] = st;
    }
}

// ---------------- final linear 128 -> 32: register-blocked GEMM (fp16 X) ------

#define FCB 128

__global__ __launch_bounds__(256) void k_fc(const _Float16* __restrict__ X,
                                            const float* __restrict__ Wf,
                                            const float* __restrict__ bf,
                                            float* __restrict__ out) {
    __shared__ float WsT[128 * 36];   // [k][o], staged once
    __shared__ float XsT[32 * 132];   // [k][n] per 32-k chunk
    int tid = threadIdx.x;
    int bm = blockIdx.x * FCB;

#pragma unroll
    for (int u = 0; u < 16; u++) {
        int idx = tid + 256 * u;          // 0..4095
        int o = idx & 31, k = idx >> 5;   // o-minor: conflict-free LDS writes
        WsT[k * 36 + o] = Wf[o * 128 + k];
    }

    int tx = tid & 7;      // outputs tx*4 .. tx*4+3
    int ty = tid >> 3;     // nodes ty*4 .. ty*4+3
    float acc[4][4];
#pragma unroll
    for (int i = 0; i < 4; i++)
#pragma unroll
        for (int j = 0; j < 4; j++) acc[i][j] = 0.f;

    for (int k0 = 0; k0 < 128; k0 += 32) {
        __syncthreads();
#pragma unroll
        for (int u = 0; u < 2; u++) {
            int idx = tid + 256 * u;      // 0..511
            int nn = idx & 127, c = idx >> 7;
            int gn = bm + nn;
            f16x8 v = {0, 0, 0, 0, 0, 0, 0, 0};
            if (gn < N_NODES) v = *(const f16x8*)&X[(size_t)gn * F + k0 + c * 8];
#pragma unroll
            for (int j = 0; j < 8; j++)
                XsT[(c * 8 + j) * 132 + nn] = (float)v[j];
        }
        __syncthreads();

#pragma unroll
        for (int kk = 0; kk < 32; kk++) {
            float4 xv = *(float4*)&XsT[kk * 132 + ty * 4];
            float4 wv = *(float4*)&WsT[(k0 + kk) * 36 + tx * 4];
            float xs[4] = {xv.x, xv.y, xv.z, xv.w};
            float ws[4] = {wv.x, wv.y, wv.z, wv.w};
#pragma unroll
            for (int i = 0; i < 4; i++)
#pragma unroll
                for (int j = 0; j < 4; j++)
                    acc[i][j] = fmaf(xs[i], ws[j], acc[i][j]);
        }
    }

    float4 bv = *(const float4*)&bf[tx * 4];
#pragma unroll
    for (int i = 0; i < 4; i++) {
        int n = bm + ty * 4 + i;
        if (n < N_NODES) {
            float4 o4 = make_float4(acc[i][0] + bv.x, acc[i][1] + bv.y,
                                    acc[i][2] + bv.z, acc[i][3] + bv.w);
            *(float4*)&out[n * 32 + tx * 4] = o4;
        }
    }
}

// ---------------- launch ----------------

extern "C" void kernel_launch(void* const* d_in, const int* in_sizes, int n_in,
                              void* d_out, int out_size, void* d_ws, size_t ws_size,
                              hipStream_t stream) {
    const float* x      = (const float*)d_in[0];   // [N,128]
    const float* Ws     = (const float*)d_in[1];   // [3,128,128]
    const float* a_src  = (const float*)d_in[2];   // [3,4,32]
    const float* a_dst  = (const float*)d_in[3];   // [3,4,32]
    const float* cbias  = (const float*)d_in[4];   // [3,128]
    const float* Wf     = (const float*)d_in[5];   // [32,128]
    const float* bf     = (const float*)d_in[6];   // [32]
    const int*   ei     = (const int*)d_in[7];     // [2,800000]
    float* out = (float*)d_out;

    char* p = (char*)d_ws;
    auto carve = [&](size_t bytes) {
        char* r = p;
        p += (bytes + 255) & ~(size_t)255;
        return r;
    };
    _Float16* xA   = (_Float16*)carve((size_t)N_NODES * F * 2);
    _Float16* xB   = (_Float16*)carve((size_t)N_NODES * F * 2);
    _Float16* xC   = (_Float16*)carve((size_t)N_NODES * F * 2);
    _Float16* hbuf = (_Float16*)carve((size_t)N_NODES * F * 2);
    _Float16* Wh   = (_Float16*)carve((size_t)3 * F * F * 2);
    _Float16* Wl   = (_Float16*)carve((size_t)3 * F * F * 2);
    float* asrc = (float*)carve((size_t)N_NODES * NHEAD * 4);
    float* adst = (float*)carve((size_t)N_NODES * NHEAD * 4);
    int* deg    = (int*)carve((size_t)N_NODES * 4);
    int* rowptr = (int*)carve((size_t)(N_NODES + 1) * 4);
    int* rank   = (int*)carve((size_t)ETOT * 4);
    int* bsum   = (int*)carve((size_t)SCAN_B * 4);
    int* col    = (int*)carve((size_t)ETOT * 4);

    // ---- weight pre-split + CSR build ----
    k_prep<<<(3 * F * F) / 256, 256, 0, stream>>>(Ws, Wh, Wl);
    hipMemsetAsync(deg, 0, (size_t)N_NODES * 4, stream);
    k_deg<<<(ETOT + 255) / 256, 256, 0, stream>>>(ei, deg, rank);
    k_scan1<<<NBLK, SCAN_B, 0, stream>>>(deg, bsum);
    k_scan2<<<1, SCAN_B, 0, stream>>>(bsum);
    k_scan3<<<NBLK, SCAN_B, 0, stream>>>(deg, bsum, rowptr);
    k_fill<<<(ETOT + 255) / 256, 256, 0, stream>>>(ei, rowptr, rank, col);

    int gaggr = (N_NODES + 3) / 4;
    int ggemm = (N_NODES + GM - 1) / GM;

    // ---- 3 GAT layers ----
    k_gemm32<<<ggemm, 256, 0, stream>>>(x, Wh, Wl, a_src, a_dst, hbuf, asrc, adst);
    k_aggr<<<gaggr, 256, 0, stream>>>(hbuf, asrc, adst, rowptr, col, cbias, xA);

    k_gemm16<<<ggemm, 256, 0, stream>>>(xA, Wh + (size_t)F * F, Wl + (size_t)F * F,
                                        a_src + F, a_dst + F, hbuf, asrc, adst);
    k_aggr<<<gaggr, 256, 0, stream>>>(hbuf, asrc, adst, rowptr, col, cbias + F, xB);

    k_gemm16<<<ggemm, 256, 0, stream>>>(xB, Wh + (size_t)2 * F * F, Wl + (size_t)2 * F * F,
                                        a_src + 2 * F, a_dst + 2 * F, hbuf, asrc, adst);
    k_aggr<<<gaggr, 256, 0, stream>>>(hbuf, asrc, adst, rowptr, col, cbias + 2 * F, xC);

    // ---- final linear (fp16 input) ----
    k_fc<<<(N_NODES + FCB - 1) / FCB, 256, 0, stream>>>(xC, Wf, bf, out);
}

// Round 13
// 324.579 us; speedup vs baseline: 1.0160x; 1.0160x over previous
//
#include <hip/hip_runtime.h>
#include <hip/hip_bf16.h>
#include <math.h>

#define N_NODES 50000
#define NE      800000
#define ETOT    (NE + N_NODES)   // edges + self loops = 850000
#define F       128              // F_in == H*C
#define NHEAD   4
#define NEG     0.2f

#define SCAN_B 256
#define NBLK   ((N_NODES + SCAN_B - 1) / SCAN_B)   // 196

typedef __attribute__((ext_vector_type(8))) short bf16x8;
typedef __attribute__((ext_vector_type(4))) float f32x4;
typedef _Float16 f16x8 __attribute__((ext_vector_type(8)));

// ---------------- CSR build (atomic-free fill via rank trick) ----------------

__global__ void k_deg(const int* __restrict__ ei, int* __restrict__ deg,
                      int* __restrict__ rank) {
    int i = blockIdx.x * blockDim.x + threadIdx.x;
    if (i < ETOT) {
        int d = (i < NE) ? ei[NE + i] : (i - NE);
        rank[i] = atomicAdd(&deg[d], 1);
    }
}

__global__ void k_scan1(const int* __restrict__ deg, int* __restrict__ bsum) {
    __shared__ int sm[SCAN_B];
    int i = blockIdx.x * SCAN_B + threadIdx.x;
    sm[threadIdx.x] = (i < N_NODES) ? deg[i] : 0;
    __syncthreads();
    for (int s = SCAN_B / 2; s > 0; s >>= 1) {
        if (threadIdx.x < s) sm[threadIdx.x] += sm[threadIdx.x + s];
        __syncthreads();
    }
    if (threadIdx.x == 0) bsum[blockIdx.x] = sm[0];
}

// scan2 fused in: each block scans the 196 block-sums locally (NBLK <= 256)
// and picks its own exclusive base — saves one dispatch + its gap.
__global__ void k_scan3(const int* __restrict__ deg, const int* __restrict__ bsum,
                        int* __restrict__ rowptr) {
    __shared__ int sb[SCAN_B];
    __shared__ int sm[SCAN_B];
    int t = threadIdx.x;
    int bv = (t < NBLK) ? bsum[t] : 0;
    sb[t] = bv; __syncthreads();
    for (int s = 1; s < SCAN_B; s <<= 1) {
        int a = (t >= s) ? sb[t - s] : 0;
        __syncthreads();
        sb[t] += a;
        __syncthreads();
    }
    int base = (blockIdx.x == 0) ? 0 : sb[blockIdx.x - 1];

    int i = blockIdx.x * SCAN_B + t;
    int v = (i < N_NODES) ? deg[i] : 0;
    sm[t] = v; __syncthreads();
    for (int s = 1; s < SCAN_B; s <<= 1) {
        int a = (t >= s) ? sm[t - s] : 0;
        __syncthreads();
        sm[t] += a;
        __syncthreads();
    }
    int excl = sm[t] - v + base;
    if (i < N_NODES) rowptr[i] = excl;
    if (i == N_NODES - 1) rowptr[N_NODES] = excl + v;
}

__global__ void k_fill(const int* __restrict__ ei, const int* __restrict__ rowptr,
                       const int* __restrict__ rank, int* __restrict__ col) {
    int i = blockIdx.x * blockDim.x + threadIdx.x;
    if (i < ETOT) {
        int s, d;
        if (i < NE) { s = ei[i]; d = ei[NE + i]; }
        else        { s = i - NE; d = s; }
        col[rowptr[d] + rank[i]] = s;
    }
}

// ---------------- split helpers ----------------

__device__ __forceinline__ unsigned short f2bf(float x) {   // RNE truncate
    unsigned int u = __float_as_uint(x);
    u += 0x7FFFu + ((u >> 16) & 1u);
    return (unsigned short)(u >> 16);
}
__device__ __forceinline__ float bf2f(unsigned short h) {
    return __uint_as_float(((unsigned int)h) << 16);
}
__device__ __forceinline__ void cvt8(float4 a, float4 b, bf16x8* hi, bf16x8* lo) {
    float f[8] = {a.x, a.y, a.z, a.w, b.x, b.y, b.z, b.w};
    bf16x8 h, l;
#pragma unroll
    for (int j = 0; j < 8; j++) {
        unsigned short hu = f2bf(f[j]);
        h[j] = (short)hu;
        l[j] = (short)f2bf(f[j] - bf2f(hu));
    }
    *hi = h; *lo = l;
}
__device__ __forceinline__ void cvt8h(float4 a, float4 b, f16x8* hi, f16x8* lo) {
    float f[8] = {a.x, a.y, a.z, a.w, b.x, b.y, b.z, b.w};
    f16x8 h, l;
#pragma unroll
    for (int j = 0; j < 8; j++) {
        _Float16 hh = (_Float16)f[j];
        h[j] = hh;
        l[j] = (_Float16)(f[j] - (float)hh);
    }
    *hi = h; *lo = l;
}

__device__ __forceinline__ int lds_unit(int m, int q) {
    return 4 * m + (q ^ ((m >> 1) & 3));
}

#define GM 64

// ---------------- layer-1 GEMM: fp32 X, split-bf16, 3 MFMAs/tile ----------------

__global__ __launch_bounds__(256) void k_gemm(const float* __restrict__ X,
                                              const float* __restrict__ W,
                                              const float* __restrict__ a_s,
                                              const float* __restrict__ a_d,
                                              _Float16* __restrict__ hout,
                                              float* __restrict__ asrc,
                                              float* __restrict__ adst) {
    __shared__ short Ah[256 * 8], Al[256 * 8];
    __shared__ short Bh[512 * 8], Bl[512 * 8];
    int tid = threadIdx.x;
    int bm = blockIdx.x * GM;

    int am = tid >> 2, aq = tid & 3;
    int xunit = ((am >> 4) << 6) + lds_unit(am & 15, aq);
    int wj = tid >> 2, wq = tid & 3;
    int wunit = ((wj >> 4) << 6) + lds_unit(wj & 15, wq);

    int lane = tid & 63, wv = tid >> 6;
    int fm = lane & 15, fq = lane >> 4;
    int a_unit = (wv << 6) + lds_unit(fm, fq);
    int b_unit0 = lds_unit(fm, fq);

    f32x4 acc[8];
#pragma unroll
    for (int nt = 0; nt < 8; nt++) acc[nt] = (f32x4){0.f, 0.f, 0.f, 0.f};

    float4 xp0, xp1, wp0, wp1, wp2, wp3;
    int gr = bm + am;
    bool xok = (gr < N_NODES);
    const float* xrow = X + (size_t)gr * F + aq * 8;
    const float* wrow1 = W + (size_t)wj * F + wq * 8;
    const float* wrow2 = W + (size_t)(wj + 64) * F + wq * 8;
    float4 z4 = make_float4(0.f, 0.f, 0.f, 0.f);

    auto load_tile = [&](int k0) {
        xp0 = xok ? *(const float4*)(xrow + k0)     : z4;
        xp1 = xok ? *(const float4*)(xrow + k0 + 4) : z4;
        wp0 = *(const float4*)(wrow1 + k0);
        wp1 = *(const float4*)(wrow1 + k0 + 4);
        wp2 = *(const float4*)(wrow2 + k0);
        wp3 = *(const float4*)(wrow2 + k0 + 4);
    };
    auto store_tile = [&]() {
        bf16x8 hi, lo;
        cvt8(xp0, xp1, &hi, &lo);
        *(bf16x8*)&Ah[xunit * 8] = hi;  *(bf16x8*)&Al[xunit * 8] = lo;
        cvt8(wp0, wp1, &hi, &lo);
        *(bf16x8*)&Bh[wunit * 8] = hi;  *(bf16x8*)&Bl[wunit * 8] = lo;
        cvt8(wp2, wp3, &hi, &lo);
        *(bf16x8*)&Bh[(wunit + 256) * 8] = hi;  *(bf16x8*)&Bl[(wunit + 256) * 8] = lo;
    };

    load_tile(0);
    store_tile();
    __syncthreads();

#pragma unroll
    for (int t = 0; t < 4; t++) {
        if (t < 3) load_tile((t + 1) * 32);
        bf16x8 ah = *(bf16x8*)&Ah[a_unit * 8];
        bf16x8 al = *(bf16x8*)&Al[a_unit * 8];
#pragma unroll
        for (int nt = 0; nt < 8; nt++) {
            int bu = ((nt << 6) + b_unit0) * 8;
            bf16x8 bh = *(bf16x8*)&Bh[bu];
            bf16x8 bl = *(bf16x8*)&Bl[bu];
            acc[nt] = __builtin_amdgcn_mfma_f32_16x16x32_bf16(ah, bh, acc[nt], 0, 0, 0);
            acc[nt] = __builtin_amdgcn_mfma_f32_16x16x32_bf16(ah, bl, acc[nt], 0, 0, 0);
            acc[nt] = __builtin_amdgcn_mfma_f32_16x16x32_bf16(al, bh, acc[nt], 0, 0, 0);
        }
        __syncthreads();
        if (t < 3) { store_tile(); __syncthreads(); }
    }

    float as_v[8], ad_v[8];
#pragma unroll
    for (int nt = 0; nt < 8; nt++) {
        as_v[nt] = a_s[nt * 16 + fm];
        ad_v[nt] = a_d[nt * 16 + fm];
    }
#pragma unroll
    for (int r = 0; r < 4; r++) {
        int n = bm + wv * 16 + fq * 4 + r;
        bool ok = (n < N_NODES);
        if (ok) {
#pragma unroll
            for (int nt = 0; nt < 8; nt++)
                hout[(size_t)n * F + nt * 16 + fm] = (_Float16)acc[nt][r];
        }
        float ps[4], pd[4];
#pragma unroll
        for (int hh = 0; hh < 4; hh++) {
            ps[hh] = acc[2 * hh][r] * as_v[2 * hh] + acc[2 * hh + 1][r] * as_v[2 * hh + 1];
            pd[hh] = acc[2 * hh][r] * ad_v[2 * hh] + acc[2 * hh + 1][r] * ad_v[2 * hh + 1];
        }
#pragma unroll
        for (int s = 1; s < 16; s <<= 1) {
#pragma unroll
            for (int hh = 0; hh < 4; hh++) {
                ps[hh] += __shfl_xor(ps[hh], s);
                pd[hh] += __shfl_xor(pd[hh], s);
            }
        }
        if (ok && fm == 0) {
            *(float4*)&asrc[n * 4] = make_float4(ps[0], ps[1], ps[2], ps[3]);
            *(float4*)&adst[n * 4] = make_float4(pd[0], pd[1], pd[2], pd[3]);
        }
    }
}

// ---------------- layer-2/3 GEMM: fp16 X (exact f16 MFMA A), W split f16 hi/lo

__global__ __launch_bounds__(256) void k_gemm16(const _Float16* __restrict__ X,
                                                const float* __restrict__ W,
                                                const float* __restrict__ a_s,
                                                const float* __restrict__ a_d,
                                                _Float16* __restrict__ hout,
                                                float* __restrict__ asrc,
                                                float* __restrict__ adst) {
    __shared__ _Float16 Ahf[256 * 8];                 // 4 KB
    __shared__ _Float16 Bhf[512 * 8], Blf[512 * 8];   // 8 KB each
    int tid = threadIdx.x;
    int bm = blockIdx.x * GM;

    int am = tid >> 2, aq = tid & 3;
    int xunit = ((am >> 4) << 6) + lds_unit(am & 15, aq);
    int wj = tid >> 2, wq = tid & 3;
    int wunit = ((wj >> 4) << 6) + lds_unit(wj & 15, wq);

    int lane = tid & 63, wv = tid >> 6;
    int fm = lane & 15, fq = lane >> 4;
    int a_unit = (wv << 6) + lds_unit(fm, fq);
    int b_unit0 = lds_unit(fm, fq);

    f32x4 acc[8];
#pragma unroll
    for (int nt = 0; nt < 8; nt++) acc[nt] = (f32x4){0.f, 0.f, 0.f, 0.f};

    f16x8 xp;
    float4 wp0, wp1, wp2, wp3;
    int gr = bm + am;
    bool xok = (gr < N_NODES);
    const _Float16* xrow = X + (size_t)gr * F + aq * 8;
    const float* wrow1 = W + (size_t)wj * F + wq * 8;
    const float* wrow2 = W + (size_t)(wj + 64) * F + wq * 8;

    auto load_tile = [&](int k0) {
        f16x8 zz = {0, 0, 0, 0, 0, 0, 0, 0};
        xp = xok ? *(const f16x8*)(xrow + k0) : zz;
        wp0 = *(const float4*)(wrow1 + k0);
        wp1 = *(const float4*)(wrow1 + k0 + 4);
        wp2 = *(const float4*)(wrow2 + k0);
        wp3 = *(const float4*)(wrow2 + k0 + 4);
    };
    auto store_tile = [&]() {
        *(f16x8*)&Ahf[xunit * 8] = xp;
        f16x8 hi, lo;
        cvt8h(wp0, wp1, &hi, &lo);
        *(f16x8*)&Bhf[wunit * 8] = hi;  *(f16x8*)&Blf[wunit * 8] = lo;
        cvt8h(wp2, wp3, &hi, &lo);
        *(f16x8*)&Bhf[(wunit + 256) * 8] = hi;  *(f16x8*)&Blf[(wunit + 256) * 8] = lo;
    };

    load_tile(0);
    store_tile();
    __syncthreads();

#pragma unroll
    for (int t = 0; t < 4; t++) {
        if (t < 3) load_tile((t + 1) * 32);
        f16x8 ah = *(f16x8*)&Ahf[a_unit * 8];
#pragma unroll
        for (int nt = 0; nt < 8; nt++) {
            int bu = ((nt << 6) + b_unit0) * 8;
            f16x8 bh = *(f16x8*)&Bhf[bu];
            f16x8 bl = *(f16x8*)&Blf[bu];
            acc[nt] = __builtin_amdgcn_mfma_f32_16x16x32_f16(ah, bh, acc[nt], 0, 0, 0);
            acc[nt] = __builtin_amdgcn_mfma_f32_16x16x32_f16(ah, bl, acc[nt], 0, 0, 0);
        }
        __syncthreads();
        if (t < 3) { store_tile(); __syncthreads(); }
    }

    float as_v[8], ad_v[8];
#pragma unroll
    for (int nt = 0; nt < 8; nt++) {
        as_v[nt] = a_s[nt * 16 + fm];
        ad_v[nt] = a_d[nt * 16 + fm];
    }
#pragma unroll
    for (int r = 0; r < 4; r++) {
        int n = bm + wv * 16 + fq * 4 + r;
        bool ok = (n < N_NODES);
        if (ok) {
#pragma unroll
            for (int nt = 0; nt < 8; nt++)
                hout[(size_t)n * F + nt * 16 + fm] = (_Float16)acc[nt][r];
        }
        float ps[4], pd[4];
#pragma unroll
        for (int hh = 0; hh < 4; hh++) {
            ps[hh] = acc[2 * hh][r] * as_v[2 * hh] + acc[2 * hh + 1][r] * as_v[2 * hh + 1];
            pd[hh] = acc[2 * hh][r] * ad_v[2 * hh] + acc[2 * hh + 1][r] * ad_v[2 * hh + 1];
        }
#pragma unroll
        for (int s = 1; s < 16; s <<= 1) {
#pragma unroll
            for (int hh = 0; hh < 4; hh++) {
                ps[hh] += __shfl_xor(ps[hh], s);
                pd[hh] += __shfl_xor(pd[hh], s);
            }
        }
        if (ok && fm == 0) {
            *(float4*)&asrc[n * 4] = make_float4(ps[0], ps[1], ps[2], ps[3]);
            *(float4*)&adst[n * 4] = make_float4(pd[0], pd[1], pd[2], pd[3]);
        }
    }
}

// ---------------- fused softmax + aggregate v4 (no-max softmax) ----------------

#define EPAD 68

__global__ __launch_bounds__(256) void k_aggr(const _Float16* __restrict__ h,
                                              const float* __restrict__ asrc,
                                              const float* __restrict__ adst,
                                              const int* __restrict__ rowptr,
                                              const int* __restrict__ col,
                                              const float* __restrict__ bias,
                                              _Float16* __restrict__ xout) {
    __shared__ int   scol[4][64];
    __shared__ float swT[4][4 * EPAD];
    int wave = threadIdx.x >> 6;
    int lane = threadIdx.x & 63;
    int n = blockIdx.x * 4 + wave;
    if (n >= N_NODES) return;
    int wl = lane & 15;        // channel-octet: channels wl*8 .. wl*8+7
    int he = lane >> 4;        // gather: edge sub-index; reduce: head id
    int hc = wl >> 2;          // head of this lane's channels
    int beg = rowptr[n], end = rowptr[n + 1];
    float4 ad4 = *(const float4*)&adst[n * 4];

    float s_run = 0.f;
    float acc[8];
#pragma unroll
    for (int j = 0; j < 8; j++) acc[j] = 0.f;

    for (int base = beg; base < end; base += 64) {
        int cnt = end - base; if (cnt > 64) cnt = 64;
        int sidx = 0;
        float4 w4 = make_float4(0.f, 0.f, 0.f, 0.f);
        if (lane < cnt) {
            sidx = col[base + lane];
            float4 av = *(const float4*)&asrc[sidx * 4];
            float ex = av.x + ad4.x, ey = av.y + ad4.y,
                  ez = av.z + ad4.z, ew = av.w + ad4.w;
            ex = (ex > 0.f) ? ex : NEG * ex;
            ey = (ey > 0.f) ? ey : NEG * ey;
            ez = (ez > 0.f) ? ez : NEG * ez;
            ew = (ew > 0.f) ? ew : NEG * ew;
            w4.x = __expf(ex); w4.y = __expf(ey);
            w4.z = __expf(ez); w4.w = __expf(ew);
        }
        scol[wave][lane] = sidx;
        swT[wave][0 * EPAD + lane] = w4.x;
        swT[wave][1 * EPAD + lane] = w4.y;
        swT[wave][2 * EPAD + lane] = w4.z;
        swT[wave][3 * EPAD + lane] = w4.w;
        __builtin_amdgcn_sched_barrier(0);   // pin LDS write->read order
        float4 wv4 = *(float4*)&swT[wave][he * EPAD + wl * 4];
        float S = (wv4.x + wv4.y) + (wv4.z + wv4.w);
#pragma unroll
        for (int s = 1; s < 16; s <<= 1) S += __shfl_xor(S, s);
        s_run += S;
        __builtin_amdgcn_sched_barrier(0);
#pragma unroll 2
        for (int p = 0; p < cnt; p += 4) {
            int ep = p + he;
            int s = scol[wave][ep];
            float wgt = swT[wave][hc * EPAD + ep];
            f16x8 hv = *(const f16x8*)&h[(size_t)s * F + wl * 8];
#pragma unroll
            for (int j = 0; j < 8; j++)
                acc[j] = fmaf(wgt, (float)hv[j], acc[j]);
        }
        __builtin_amdgcn_sched_barrier(0);   // gather reads before next chunk
    }

#pragma unroll
    for (int j = 0; j < 8; j++) {
        acc[j] += __shfl_xor(acc[j], 16);
        acc[j] += __shfl_xor(acc[j], 32);
    }
    float sv = __shfl(s_run, hc * 16);
    float inv = 1.f / (sv + 1e-16f);
    float4 b0 = *(const float4*)&bias[wl * 8];
    float4 b1 = *(const float4*)&bias[wl * 8 + 4];
    float bb[8] = {b0.x, b0.y, b0.z, b0.w, b1.x, b1.y, b1.z, b1.w};
    if (he == 0) {
        f16x8 st;
#pragma unroll
        for (int j = 0; j < 8; j++)
            st[j] = (_Float16)fmaxf(fmaf(acc[j], inv, bb[j]), 0.f);
        *(f16x8*)&xout[(size_t)n * F + wl * 8] = st;
    }
}

// ---------------- final linear 128 -> 32: register-blocked GEMM (fp16 X) ------

#define FCB 128

__global__ __launch_bounds__(256) void k_fc(const _Float16* __restrict__ X,
                                            const float* __restrict__ Wf,
                                            const float* __restrict__ bf,
                                            float* __restrict__ out) {
    __shared__ float WsT[128 * 36];   // [k][o], staged once
    __shared__ float XsT[32 * 132];   // [k][n] per 32-k chunk
    int tid = threadIdx.x;
    int bm = blockIdx.x * FCB;

#pragma unroll
    for (int u = 0; u < 16; u++) {
        int idx = tid + 256 * u;          // 0..4095
        int o = idx & 31, k = idx >> 5;   // o-minor: conflict-free LDS writes
        WsT[k * 36 + o] = Wf[o * 128 + k];
    }

    int tx = tid & 7;      // outputs tx*4 .. tx*4+3
    int ty = tid >> 3;     // nodes ty*4 .. ty*4+3
    float acc[4][4];
#pragma unroll
    for (int i = 0; i < 4; i++)
#pragma unroll
        for (int j = 0; j < 4; j++) acc[i][j] = 0.f;

    for (int k0 = 0; k0 < 128; k0 += 32) {
        __syncthreads();
#pragma unroll
        for (int u = 0; u < 2; u++) {
            int idx = tid + 256 * u;      // 0..511
            int nn = idx & 127, c = idx >> 7;
            int gn = bm + nn;
            f16x8 v = {0, 0, 0, 0, 0, 0, 0, 0};
            if (gn < N_NODES) v = *(const f16x8*)&X[(size_t)gn * F + k0 + c * 8];
#pragma unroll
            for (int j = 0; j < 8; j++)
                XsT[(c * 8 + j) * 132 + nn] = (float)v[j];
        }
        __syncthreads();

#pragma unroll
        for (int kk = 0; kk < 32; kk++) {
            float4 xv = *(float4*)&XsT[kk * 132 + ty * 4];
            float4 wv = *(float4*)&WsT[(k0 + kk) * 36 + tx * 4];
            float xs[4] = {xv.x, xv.y, xv.z, xv.w};
            float ws[4] = {wv.x, wv.y, wv.z, wv.w};
#pragma unroll
            for (int i = 0; i < 4; i++)
#pragma unroll
                for (int j = 0; j < 4; j++)
                    acc[i][j] = fmaf(xs[i], ws[j], acc[i][j]);
        }
    }

    float4 bv = *(const float4*)&bf[tx * 4];
#pragma unroll
    for (int i = 0; i < 4; i++) {
        int n = bm + ty * 4 + i;
        if (n < N_NODES) {
            float4 o4 = make_float4(acc[i][0] + bv.x, acc[i][1] + bv.y,
                                    acc[i][2] + bv.z, acc[i][3] + bv.w);
            *(float4*)&out[n * 32 + tx * 4] = o4;
        }
    }
}

// ---------------- launch ----------------

extern "C" void kernel_launch(void* const* d_in, const int* in_sizes, int n_in,
                              void* d_out, int out_size, void* d_ws, size_t ws_size,
                              hipStream_t stream) {
    const float* x      = (const float*)d_in[0];   // [N,128]
    const float* Ws     = (const float*)d_in[1];   // [3,128,128]
    const float* a_src  = (const float*)d_in[2];   // [3,4,32]
    const float* a_dst  = (const float*)d_in[3];   // [3,4,32]
    const float* cbias  = (const float*)d_in[4];   // [3,128]
    const float* Wf     = (const float*)d_in[5];   // [32,128]
    const float* bf     = (const float*)d_in[6];   // [32]
    const int*   ei     = (const int*)d_in[7];     // [2,800000]
    float* out = (float*)d_out;

    char* p = (char*)d_ws;
    auto carve = [&](size_t bytes) {
        char* r = p;
        p += (bytes + 255) & ~(size_t)255;
        return r;
    };
    _Float16* xA   = (_Float16*)carve((size_t)N_NODES * F * 2);
    _Float16* xB   = (_Float16*)carve((size_t)N_NODES * F * 2);
    _Float16* xC   = (_Float16*)carve((size_t)N_NODES * F * 2);
    _Float16* hbuf = (_Float16*)carve((size_t)N_NODES * F * 2);
    float* asrc = (float*)carve((size_t)N_NODES * NHEAD * 4);
    float* adst = (float*)carve((size_t)N_NODES * NHEAD * 4);
    int* deg    = (int*)carve((size_t)N_NODES * 4);
    int* rowptr = (int*)carve((size_t)(N_NODES + 1) * 4);
    int* rank   = (int*)carve((size_t)ETOT * 4);
    int* bsum   = (int*)carve((size_t)SCAN_B * 4);
    int* col    = (int*)carve((size_t)ETOT * 4);

    // ---- CSR build (dst-sorted adjacency), atomic-free fill ----
    hipMemsetAsync(deg, 0, (size_t)N_NODES * 4, stream);
    k_deg<<<(ETOT + 255) / 256, 256, 0, stream>>>(ei, deg, rank);
    k_scan1<<<NBLK, SCAN_B, 0, stream>>>(deg, bsum);
    k_scan3<<<NBLK, SCAN_B, 0, stream>>>(deg, bsum, rowptr);   // scan2 fused in
    k_fill<<<(ETOT + 255) / 256, 256, 0, stream>>>(ei, rowptr, rank, col);

    int gaggr = (N_NODES + 3) / 4;
    int ggemm = (N_NODES + GM - 1) / GM;

    // ---- 3 GAT layers ----
    k_gemm<<<ggemm, 256, 0, stream>>>(x, Ws, a_src, a_dst, hbuf, asrc, adst);
    k_aggr<<<gaggr, 256, 0, stream>>>(hbuf, asrc, adst, rowptr, col, cbias, xA);

    k_gemm16<<<ggemm, 256, 0, stream>>>(xA, Ws + (size_t)F * F, a_src + F, a_dst + F,
                                        hbuf, asrc, adst);
    k_aggr<<<gaggr, 256, 0, stream>>>(hbuf, asrc, adst, rowptr, col, cbias + F, xB);

    k_gemm16<<<ggemm, 256, 0, stream>>>(xB, Ws + (size_t)2 * F * F, a_src + 2 * F,
                                        a_dst + 2 * F, hbuf, asrc, adst);
    k_aggr<<<gaggr, 256, 0, stream>>>(hbuf, asrc, adst, rowptr, col, cbias + 2 * F, xC);

    // ---- final linear (fp16 input) ----
    k_fc<<<(N_NODES + FCB - 1) / FCB, 256, 0, stream>>>(xC, Wf, bf, out);
}